// Round 3
// baseline (36.290 us; speedup 1.0000x reference)
//
#include <hip/hip_runtime.h>

#define NB 8
#define SS 2048
#define DD 128
#define SCALE 0.35355339059327373f

typedef _Float16 f16x8 __attribute__((ext_vector_type(8)));
typedef float f32x16 __attribute__((ext_vector_type(16)));
typedef unsigned short u16;
typedef u16 u16x8 __attribute__((ext_vector_type(8)));

__device__ __forceinline__ unsigned pkrtz(float a, float b) {
    unsigned w;
    asm("v_cvt_pkrtz_f16_f32 %0, %1, %2" : "=v"(w) : "v"(a), "v"(b));
    return w;
}

// async global->LDS, 16B/lane, LDS dest = wave-uniform base + lane*16
__device__ __forceinline__ void gload_lds16(const u16* g, u16* l) {
    __builtin_amdgcn_global_load_lds(
        (const __attribute__((address_space(1))) unsigned*)g,
        (__attribute__((address_space(3))) unsigned*)l, 16, 0, 0);
}

// ---------------- Kernel 1: U = quantum_measure(x, theta) ----------------
// Emits TWO fragment-order f16 layouts (per batch, per 32-row s-tile t):
//  G1 : chunk16B[t*512 + kc*64 + hi*32 + r]  holds U[t*32+r][kc*16+hi*8 + 0..7]
//  G2t: chunk16B[t*512 + (dt*2+kc2)*64 + hi*32 + lo5] holds U[t*32+kc2*16+hi*8+u][dt*32+lo5]
__global__ __launch_bounds__(512) void qmeasure_kernel(const float* __restrict__ x,
                                                       const float* __restrict__ theta,
                                                       u16* __restrict__ G1,
                                                       u16* __restrict__ G2) {
    __shared__ u16 olds[32][128];
    const int bid = blockIdx.x;
    const int b = bid & 7;
    const int t = bid >> 3;
    const int tid = threadIdx.x;
    const int s = tid >> 4;     // 0..31
    const int c = tid & 15;     // 16B chunk (head) index 0..15

    float th[8];
    *(float4*)th = *(const float4*)theta;
    *(float4*)(th + 4) = *(const float4*)(theta + 4);

    const float* xp = x + (((size_t)b * SS + t * 32 + s) * DD) + c * 8;
    float4 a = *(const float4*)xp;
    float4 a2 = *(const float4*)(xp + 4);
    float cc[8];
    cc[0] = __cosf(a.x + th[0]);  cc[1] = __cosf(a.y + th[1]);
    cc[2] = __cosf(a.z + th[2]);  cc[3] = __cosf(a.w + th[3]);
    cc[4] = __cosf(a2.x + th[4]); cc[5] = __cosf(a2.y + th[5]);
    cc[6] = __cosf(a2.z + th[6]); cc[7] = __cosf(a2.w + th[7]);
    float o[8];
    o[1] = cc[0] * cc[1];
    o[2] = o[1] * cc[2]; o[3] = o[2] * cc[3]; o[4] = o[3] * cc[4];
    o[5] = o[4] * cc[5]; o[6] = o[5] * cc[6]; o[7] = o[6] * cc[7];
    float z = cc[1] * cc[2]; z *= cc[3]; z *= cc[4]; z *= cc[5]; z *= cc[6]; z *= cc[7];
    o[0] = z;

    u16x8 w;
#pragma unroll
    for (int e = 0; e < 8; ++e) w[e] = __builtin_bit_cast(u16, (_Float16)o[e]);

    {
        const int chunk = t * 512 + (c >> 1) * 64 + (c & 1) * 32 + s;
        *(u16x8*)(G1 + (size_t)b * (SS * DD) + (size_t)chunk * 8) = w;
    }
    *(u16x8*)&olds[s][c * 8] = w;
    __syncthreads();
    {
        const int lo5 = tid & 31;
        const int hi = (tid >> 5) & 1;
        const int dkc = tid >> 6;          // 0..7 = dt*2+kc2
        const int dt = dkc >> 1, kc2 = dkc & 1;
        u16x8 g;
#pragma unroll
        for (int u = 0; u < 8; ++u) g[u] = olds[kc2 * 16 + hi * 8 + u][dt * 32 + lo5];
        const int chunk = t * 512 + dkc * 64 + hi * 32 + lo5;
        *(u16x8*)(G2 + (size_t)b * (SS * DD) + (size_t)chunk * 8) = g;
    }
}

// ---------------- Kernel 2: flash attention, LDS-staged 2-phase pipeline ----------------
// grid 256 = 8 batches (bid&7, XCD-pinned) x 32 q-groups of 64 rows. 512 thr = 8 waves
// = 2 qw (q sub-tile of 32) x 4 kq (KV quarter). Per iter: wave(qw=0,kq) stages next
// K-tile, wave(qw=1,kq) stages next V^T-tile via global_load_lds (fragment-linear, so
// LDS stays linear and ds_read_b128 is conflict-free). Both qw waves consume the same
// staged tiles -> L2 ingress halves to 256 MB. Double-buffered, stage-before-compute.
__global__ __launch_bounds__(512, 2) void qattn_kernel(const u16* __restrict__ G1g,
                                                       const u16* __restrict__ G2g,
                                                       float* __restrict__ out) {
    __shared__ __align__(16) u16 sb[2][2][4][4096];   // [dbuf][K/V][kq][8KB tile] = 128 KB

    const int tid = threadIdx.x;
    const int lane = tid & 63;
    const int wave = tid >> 6;
    const int lo5 = lane & 31;
    const int hi = lane >> 5;
    const int qw = wave & 1;
    const int kq = wave >> 1;    // KV quarter 0..3
    const int bid = blockIdx.x;
    const int b = bid & 7;
    const int qg = bid >> 3;     // 0..31

    const u16* G1b = G1g + (size_t)b * (SS * DD);
    const u16* G2b = G2g + (size_t)b * (SS * DD);

    // Q fragments (B-operand), loaded once from global
    f16x8 qf[8];
    {
        const u16* qp = G1b + (size_t)(qg * 2 + qw) * 4096 + lane * 8;
#pragma unroll
        for (int kc = 0; kc < 8; ++kc) qf[kc] = *(const f16x8*)(qp + kc * 512);
    }

    f32x16 accT[4];
#pragma unroll
    for (int dt = 0; dt < 4; ++dt)
#pragma unroll
        for (int e = 0; e < 16; ++e) accT[dt][e] = 0.f;
    float m = -3.0e38f, l = 0.f;

    // prologue: stage tile it=0 into buf 0 (qw0 -> K, qw1 -> V^T)
    {
        const int t = kq * 16;
        const u16* src = (qw == 0 ? G1b : G2b) + (size_t)t * 4096 + lane * 8;
        u16* dst = &sb[0][qw][kq][0];
#pragma unroll
        for (int w = 0; w < 8; ++w) gload_lds16(src + w * 512, dst + w * 512);
    }
    __syncthreads();

    for (int it = 0; it < 16; ++it) {
        const int cur = it & 1;
        // stage next tile first (latency hides under this iter's compute)
        if (it < 15) {
            const int t = kq * 16 + it + 1;
            const u16* src = (qw == 0 ? G1b : G2b) + (size_t)t * 4096 + lane * 8;
            u16* dst = &sb[cur ^ 1][qw][kq][0];
#pragma unroll
            for (int w = 0; w < 8; ++w) gload_lds16(src + w * 512, dst + w * 512);
        }

        const u16* Kb = &sb[cur][0][kq][0];
        const u16* Vb = &sb[cur][1][kq][0];

        // K A-frags from LDS (contiguous b128)
        f16x8 kf[8];
#pragma unroll
        for (int kc = 0; kc < 8; ++kc) kf[kc] = *(const f16x8*)(Kb + kc * 512 + lane * 8);

        // S^T = K . Q^T
        f32x16 acc;
#pragma unroll
        for (int e = 0; e < 16; ++e) acc[e] = 0.f;
#pragma unroll
        for (int kc = 0; kc < 8; ++kc)
            acc = __builtin_amdgcn_mfma_f32_32x32x16_f16(kf[kc], qf[kc], acc, 0, 0, 0);

        // V^T A-frags from LDS (issue early; consumed after softmax)
        f16x8 vf[8];
#pragma unroll
        for (int j = 0; j < 8; ++j) vf[j] = *(const f16x8*)(Vb + j * 512 + lane * 8);

        // online softmax (16 kv vals/lane, partner lane ^32 shares q), defer-max THR=8
        float tmax = acc[0];
#pragma unroll
        for (int r = 1; r < 16; ++r) tmax = fmaxf(tmax, acc[r]);
        tmax *= SCALE;
        tmax = fmaxf(tmax, __shfl_xor(tmax, 32));
        if (!__all(tmax <= m + 8.f)) {
            const float mnew = fmaxf(m, tmax);
            const float corr = __expf(m - mnew);
            l *= corr;
#pragma unroll
            for (int dt = 0; dt < 4; ++dt)
#pragma unroll
                for (int e = 0; e < 16; ++e) accT[dt][e] *= corr;
            m = mnew;
        }
        float rowsum = 0.f;
#pragma unroll
        for (int r = 0; r < 16; ++r) {
            float p = __expf(acc[r] * SCALE - m);
            acc[r] = p;
            rowsum += p;
        }
        rowsum += __shfl_xor(rowsum, 32);
        l += rowsum;

        // P^T B-frags (2): elems = kv 16*kc2+8*hi+u
        f16x8 pa[2];
#pragma unroll
        for (int kc2 = 0; kc2 < 2; ++kc2) {
            const int r0 = kc2 * 8;
            unsigned w0 = pkrtz(acc[r0 + 0], acc[r0 + 1]);
            unsigned w2 = pkrtz(acc[r0 + 4], acc[r0 + 5]);
            asm("v_permlane32_swap_b32 %0, %1" : "+v"(w0), "+v"(w2));
            unsigned w1 = pkrtz(acc[r0 + 2], acc[r0 + 3]);
            unsigned w3 = pkrtz(acc[r0 + 6], acc[r0 + 7]);
            asm("v_permlane32_swap_b32 %0, %1" : "+v"(w1), "+v"(w3));
            union { unsigned w[4]; f16x8 v; } u;
            u.w[0] = w0; u.w[1] = w1; u.w[2] = w2; u.w[3] = w3;
            pa[kc2] = u.v;
        }

        // O^T += V^T . P^T
#pragma unroll
        for (int dt = 0; dt < 4; ++dt) {
            f32x16 a = accT[dt];
#pragma unroll
            for (int kc2 = 0; kc2 < 2; ++kc2)
                a = __builtin_amdgcn_mfma_f32_32x32x16_f16(vf[dt * 2 + kc2], pa[kc2], a, 0, 0, 0);
            accT[dt] = a;
        }

        __syncthreads();   // drains vmcnt (next tile landed) + lgkmcnt, swaps buffers
    }

    // ---- 4-way KV merge via LDS (staging buffers are dead; alias them) ----
    float* obuf = (float*)(&sb[0][0][0][0]);                       // [2][3][2][16][64] f32 = 48 KB
    float* mlb = (float*)((unsigned char*)(&sb[0][0][0][0]) + 49152);  // [2][3][2][32] f32
    float* orow = out + ((size_t)b * SS + qg * 64 + qw * 32 + lo5) * DD;
#pragma unroll
    for (int half = 0; half < 2; ++half) {
        if (kq > 0) {
            if (half == 0 && hi == 0) {
                mlb[((qw * 3 + (kq - 1)) * 2 + 0) * 32 + lo5] = m;
                mlb[((qw * 3 + (kq - 1)) * 2 + 1) * 32 + lo5] = l;
            }
#pragma unroll
            for (int dh = 0; dh < 2; ++dh)
#pragma unroll
                for (int r = 0; r < 16; ++r)
                    obuf[(((qw * 3 + (kq - 1)) * 2 + dh) * 16 + r) * 64 + lane] =
                        accT[half * 2 + dh][r];
        }
        __syncthreads();
        if (kq == 0) {
            const float mj0 = mlb[((qw * 3 + 0) * 2 + 0) * 32 + lo5];
            const float lj0 = mlb[((qw * 3 + 0) * 2 + 1) * 32 + lo5];
            const float mj1 = mlb[((qw * 3 + 1) * 2 + 0) * 32 + lo5];
            const float lj1 = mlb[((qw * 3 + 1) * 2 + 1) * 32 + lo5];
            const float mj2 = mlb[((qw * 3 + 2) * 2 + 0) * 32 + lo5];
            const float lj2 = mlb[((qw * 3 + 2) * 2 + 1) * 32 + lo5];
            const float ms = fmaxf(fmaxf(m, mj0), fmaxf(mj1, mj2));
            const float w0 = __expf(m - ms), w1 = __expf(mj0 - ms);
            const float w2 = __expf(mj1 - ms), w3 = __expf(mj2 - ms);
            const float linv = 1.f / (l * w0 + lj0 * w1 + lj1 * w2 + lj2 * w3);
#pragma unroll
            for (int dh = 0; dh < 2; ++dh) {
                const int dt = half * 2 + dh;
#pragma unroll
                for (int r = 0; r < 16; ++r) {
                    const float o = accT[dt][r] * w0 +
                                    obuf[(((qw * 3 + 0) * 2 + dh) * 16 + r) * 64 + lane] * w1 +
                                    obuf[(((qw * 3 + 1) * 2 + dh) * 16 + r) * 64 + lane] * w2 +
                                    obuf[(((qw * 3 + 2) * 2 + dh) * 16 + r) * 64 + lane] * w3;
                    const int drow = (r & 3) + 8 * (r >> 2) + 4 * hi;
                    orow[dt * 32 + drow] = o * linv;
                }
            }
        }
        __syncthreads();
    }
}

extern "C" void kernel_launch(void* const* d_in, const int* in_sizes, int n_in,
                              void* d_out, int out_size, void* d_ws, size_t ws_size,
                              hipStream_t stream) {
    const float* x = (const float*)d_in[0];
    const float* theta = (const float*)d_in[1];
    float* outp = (float*)d_out;
    u16* G1 = (u16*)d_ws;                       // 8*2048*128 f16 = 4 MB
    u16* G2 = G1 + (size_t)NB * SS * DD;        // +4 MB

    qmeasure_kernel<<<512, 512, 0, stream>>>(x, theta, G1, G2);
    qattn_kernel<<<256, 512, 0, stream>>>(G1, G2, outp);
}